// Round 2
// baseline (252.867 us; speedup 1.0000x reference)
//
#include <hip/hip_runtime.h>

// ---------------------------------------------------------------------------
// SparseAttention fused pipeline for MI355X (gfx950).
//   B=2, S=2048, H=1024, NH=16, HD=64.
// Pipeline: cast f32->bf16 -> threefry mask bitset -> QKV MFMA GEMM (V written
// transposed) -> fused dense-softmax attention (mask multiplicative => masked
// scores are 0 => exp(0)=1 stays in the softmax; no max subtraction needed).
// Mask PRNG: JAX partitionable threefry (default since jax 0.4.36):
//   bits(i) = y0 ^ y1, (y0,y1) = threefry2x32(key=(0,42), counts=(i>>32, i&0xffffffff))
// ---------------------------------------------------------------------------

typedef unsigned int u32;
typedef unsigned short u16;
typedef float f32x4 __attribute__((ext_vector_type(4)));
typedef short s16x8 __attribute__((ext_vector_type(8)));
typedef u32  u32x4 __attribute__((ext_vector_type(4)));
typedef u16  u16x4 __attribute__((ext_vector_type(4)));

__device__ __forceinline__ u16 f2bf(float f) {
  u32 u = __builtin_bit_cast(u32, f);
  return (u16)((u + 0x7FFFu + ((u >> 16) & 1u)) >> 16);   // RNE
}

// async global->LDS, 16B per lane (dest must be wave-uniform base + lane*16)
__device__ __forceinline__ void async16(void* lds, const void* g) {
  __builtin_amdgcn_global_load_lds((const __attribute__((address_space(1))) u32*)g,
                                   (__attribute__((address_space(3))) u32*)lds, 16, 0, 0);
}

// ---------------------------------------------------------------------------
// f32 -> bf16 cast
// ---------------------------------------------------------------------------
__global__ __launch_bounds__(256) void cast_kernel(const float* __restrict__ src,
                                                   u16* __restrict__ dst, int n4) {
  int i = blockIdx.x * 256 + threadIdx.x;
  if (i < n4) {
    float4 v = ((const float4*)src)[i];
    u16x4 o = { f2bf(v.x), f2bf(v.y), f2bf(v.z), f2bf(v.w) };
    ((u16x4*)dst)[i] = o;
  }
}

// ---------------------------------------------------------------------------
// JAX threefry2x32, key = (0, 42)  (jax.random.key(42))
// ---------------------------------------------------------------------------
__device__ __forceinline__ void threefry(u32 x0, u32 x1, u32& y0, u32& y1) {
  const u32 k0 = 0u, k1 = 42u, k2 = 0u ^ 42u ^ 0x1BD11BDAu;
  x0 += k0; x1 += k1;
#define TFR(r) { x0 += x1; x1 = (x1 << r) | (x1 >> (32 - r)); x1 ^= x0; }
  TFR(13) TFR(15) TFR(26) TFR(6)  x0 += k1; x1 += k2 + 1u;
  TFR(17) TFR(29) TFR(16) TFR(24) x0 += k2; x1 += k0 + 2u;
  TFR(13) TFR(15) TFR(26) TFR(6)  x0 += k0; x1 += k1 + 3u;
  TFR(17) TFR(29) TFR(16) TFR(24) x0 += k1; x1 += k2 + 4u;
  TFR(13) TFR(15) TFR(26) TFR(6)  x0 += k2; x1 += k0 + 5u;
#undef TFR
  y0 = x0; y1 = x1;
}

// ---------------------------------------------------------------------------
// Mask: band(+-2) OR top-204 columns of threefry-uniform row.
// Partitionable mode: counts = 64-bit iota split (hi, lo) = (0, flat);
// 32-bit bits = y0 ^ y1. u = bitcast((bits>>9)|0x3f800000)-1 is strictly
// monotone in bits>>9, so rank on the 23-bit key; ties -> lower col
// (XLA stable top_k). Output: bitset [2048][64] u32.
// ---------------------------------------------------------------------------
#define NRAND 204

__global__ __launch_bounds__(256) void mask_kernel(u32* __restrict__ maskbits) {
  __shared__ u32 hist[256];
  __shared__ u32 mwords[64];
  __shared__ u32 candV[128];
  __shared__ u32 candC[128];
  __shared__ u32 used[128];
  __shared__ u32 scal[4];   // 0:bin 1:need 2:candCount

  const int tid = threadIdx.x;
  const int row = blockIdx.x;
  hist[tid] = 0;
  if (tid < 64) mwords[tid] = 0;
  if (tid < 128) used[tid] = 0;
  if (tid == 0) scal[2] = 0;
  __syncthreads();

  u32 k23[8];
#pragma unroll
  for (int j = 0; j < 8; ++j) {
    u32 c = (u32)tid * 8u + (u32)j;
    u32 flat = (u32)row * 2048u + c;          // < 2^22, so hi word = 0
    u32 y0, y1; threefry(0u, flat, y0, y1);   // counts (0, flat)
    u32 bits = y0 ^ y1;                       // partitionable 32-bit output
    k23[j] = bits >> 9;
    atomicAdd(&hist[k23[j] >> 15], 1u);
  }
  __syncthreads();
  // suffix sums (Hillis-Steele): hist[v] := #values with top8 >= v
  for (int off = 1; off < 256; off <<= 1) {
    u32 add = (tid + off < 256) ? hist[tid + off] : 0u;
    __syncthreads();
    hist[tid] += add;
    __syncthreads();
  }
  u32 Sv = hist[tid];
  u32 Sn = (tid < 255) ? hist[tid + 1] : 0u;
  if (Sv >= NRAND && Sn < NRAND) { scal[0] = (u32)tid; scal[1] = NRAND - Sn; }
  __syncthreads();
  const u32 bin = scal[0];
  const u32 need = scal[1];
#pragma unroll
  for (int j = 0; j < 8; ++j) {
    if ((k23[j] >> 15) == bin) {
      u32 p = atomicAdd(&scal[2], 1u);
      if (p < 128u) { candV[p] = k23[j]; candC[p] = (u32)tid * 8u + (u32)j; }
    }
  }
  __syncthreads();
  if (tid == 0) {  // boundary-bin refinement: top `need` by (value desc, col asc)
    int n = (int)(scal[2] < 128u ? scal[2] : 128u);
    for (u32 t = 0; t < need; ++t) {
      int best = -1;
      for (int i2 = 0; i2 < n; ++i2) {
        if (used[i2]) continue;
        if (best < 0 || candV[i2] > candV[best] ||
            (candV[i2] == candV[best] && candC[i2] < candC[best])) best = i2;
      }
      if (best < 0) break;
      used[best] = 1;
      atomicOr(&mwords[candC[best] >> 5], 1u << (candC[best] & 31u));
    }
  }
#pragma unroll
  for (int j = 0; j < 8; ++j) {   // everything strictly above the bin is in
    u32 c = (u32)tid * 8u + (u32)j;
    if ((k23[j] >> 15) > bin) atomicOr(&mwords[c >> 5], 1u << (c & 31u));
  }
  if (tid < 5) {                  // band
    int c = row - 2 + tid;
    if (c >= 0 && c < 2048) atomicOr(&mwords[c >> 5], 1u << (c & 31u));
  }
  __syncthreads();
  if (tid < 64) maskbits[row * 64 + tid] = mwords[tid];
}

// ---------------------------------------------------------------------------
// QKV projection: Y = X @ W^T + b  (both operands K-contiguous).
// 128x128 tile, BK=32, 4 waves (2x2 of 64x64), m97-style global_load_lds.
// z=0: Q (scaled 1/8, layout [bh][s][d]); z=1: K; z=2: V written TRANSPOSED
// as Vt[bh][d][s] via LDS exchange.
// LDS chunk swizzle: chunk' = chunk ^ ((row>>1)&3)  (applied on global src,
// since global_load_lds dest must stay linear).
// ---------------------------------------------------------------------------
__global__ __launch_bounds__(256) void gemm_qkv(
    const u16* __restrict__ Xbf, const u16* __restrict__ Wbf3,
    const float* __restrict__ bq, const float* __restrict__ bk,
    const float* __restrict__ bv,
    u16* __restrict__ Qbf, u16* __restrict__ Kbf, u16* __restrict__ VtB) {
  __shared__ u16 smem[128 * 136];           // 34816 B: As+Bs (16KB) / V ctile
  u16* As = smem;                            // [128][32]
  u16* Bs = smem + 4096;                     // [128][32]

  const int tid  = threadIdx.x;
  const int lane = tid & 63;
  const int w    = tid >> 6;
  const int wr = w >> 1, wc = w & 1;
  const int l15 = lane & 15, l4 = lane >> 4;
  const int mBase = blockIdx.x * 128;
  const int nBase = blockIdx.y * 128;
  const int z = blockIdx.z;
  const u16* Bmat = Wbf3 + z * 1048576;
  const float* bias = (z == 0) ? bq : (z == 1) ? bk : bv;

  const int ci1 = tid, ci2 = tid + 256;
  const int r1 = ci1 >> 2, c1 = ci1 & 3, cc1 = c1 ^ ((r1 >> 1) & 3);
  const int r2 = ci2 >> 2, c2 = ci2 & 3, cc2 = c2 ^ ((r2 >> 1) & 3);

  f32x4 acc[4][4];
#pragma unroll
  for (int i = 0; i < 4; ++i)
#pragma unroll
    for (int j = 0; j < 4; ++j) acc[i][j] = {0.f, 0.f, 0.f, 0.f};

  for (int k0 = 0; k0 < 1024; k0 += 32) {
    async16(As + ci1 * 8, Xbf + (mBase + r1) * 1024 + k0 + cc1 * 8);
    async16(As + ci2 * 8, Xbf + (mBase + r2) * 1024 + k0 + cc2 * 8);
    async16(Bs + ci1 * 8, Bmat + (nBase + r1) * 1024 + k0 + cc1 * 8);
    async16(Bs + ci2 * 8, Bmat + (nBase + r2) * 1024 + k0 + cc2 * 8);
    __syncthreads();
    s16x8 a[4], b[4];
#pragma unroll
    for (int f = 0; f < 4; ++f) {
      int rl = wr * 64 + f * 16 + l15;
      a[f] = *(const s16x8*)(As + rl * 32 + ((l4 ^ ((rl >> 1) & 3)) * 8));
    }
#pragma unroll
    for (int f = 0; f < 4; ++f) {
      int rl = wc * 64 + f * 16 + l15;
      b[f] = *(const s16x8*)(Bs + rl * 32 + ((l4 ^ ((rl >> 1) & 3)) * 8));
    }
#pragma unroll
    for (int i = 0; i < 4; ++i)
#pragma unroll
      for (int j = 0; j < 4; ++j)
        acc[i][j] = __builtin_amdgcn_mfma_f32_16x16x32_bf16(a[i], b[j], acc[i][j], 0, 0, 0);
    __syncthreads();
  }

  const float scale = (z == 0) ? 0.125f : 1.0f;   // fold 1/sqrt(64) into Q
  if (z < 2) {
    u16* dst = (z == 0) ? Qbf : Kbf;
#pragma unroll
    for (int i = 0; i < 4; ++i)
#pragma unroll
      for (int j = 0; j < 4; ++j) {
        int ng = nBase + wc * 64 + j * 16 + l15;
        int h = ng >> 6, d = ng & 63;
        float bb = bias[ng];
#pragma unroll
        for (int r = 0; r < 4; ++r) {
          int mg = mBase + wr * 64 + i * 16 + l4 * 4 + r;
          int bbi = mg >> 11, s = mg & 2047;
          dst[(((bbi * 16 + h) * 2048 + s) * 64) + d] = f2bf((acc[i][j][r] + bb) * scale);
        }
      }
  } else {
    // V: transpose 128x128 tile in LDS (ctile[n][m], stride 136), write Vt[bh][d][s]
    u16* ct = smem;
#pragma unroll
    for (int i = 0; i < 4; ++i)
#pragma unroll
      for (int j = 0; j < 4; ++j) {
        int nl = wc * 64 + j * 16 + l15;
        int ml = wr * 64 + i * 16 + l4 * 4;
        float bb = bias[nBase + nl];
        u16x4 p = { f2bf(acc[i][j][0] + bb), f2bf(acc[i][j][1] + bb),
                    f2bf(acc[i][j][2] + bb), f2bf(acc[i][j][3] + bb) };
        *(u16x4*)(ct + nl * 136 + ml) = p;
      }
    __syncthreads();
#pragma unroll
    for (int it = 0; it < 8; ++it) {
      int ci = tid + it * 256;                 // 2048 chunks of 8 bf16
      int nl = ci >> 4, m8 = ci & 15;
      int ng = nBase + nl, mg = mBase + m8 * 8;
      int h = ng >> 6, d = ng & 63;
      int bbi = mg >> 11, s = mg & 2047;
      s16x8 v = *(const s16x8*)(ct + nl * 136 + m8 * 8);
      *(s16x8*)(VtB + (((bbi * 16 + h) * 64 + d) * 2048) + s) = v;
    }
  }
}

// ---------------------------------------------------------------------------
// Fused attention. Block = (64 q-rows, one bh). 4 waves, each owns 16 q-rows.
// Per 64-key tile: S=Q@K^T (MFMA) -> mask*exp (exp(0)=1 for masked) -> P via
// per-wave LDS -> ctx += P@V (MFMA, V pre-transposed). rowsum in registers;
// final: shuffle-reduce over 16 cols, divide, store f32.
// K/V tiles staged with global_load_lds; 128B rows XOR-swizzled (c ^ (row&7))
// on the GLOBAL source so fragment ds_read_b128 is ~2-way max.
// ---------------------------------------------------------------------------
__global__ __launch_bounds__(256) void attn_kernel(
    const u16* __restrict__ Qbf, const u16* __restrict__ Kbf,
    const u16* __restrict__ Vt, const u32* __restrict__ maskbits,
    float* __restrict__ out) {
  __shared__ u16 KbS[64 * 64];
  __shared__ u16 VtS[64 * 64];
  __shared__ u32 maskT[64 * 68];   // [word][qrow] (padded)
  __shared__ u16 Pls[4][16 * 72];  // per-wave P tile [qrow16][key64+pad]

  const int tid  = threadIdx.x;
  const int lane = tid & 63;
  const int w    = tid >> 6;
  const int l15 = lane & 15, l4 = lane >> 4;
  const int qt = blockIdx.x;
  const int bh = blockIdx.y;
  const int qbase = qt * 64;

  for (int idx = tid; idx < 4096; idx += 256) {
    int ww = idx & 63, qr = idx >> 6;
    maskT[ww * 68 + qr] = maskbits[(qbase + qr) * 64 + ww];
  }

  const int qrow = qbase + w * 16 + l15;
  const u16* qp = Qbf + ((bh * 2048 + qrow) * 64) + l4 * 8;
  s16x8 qa0 = *(const s16x8*)(qp);
  s16x8 qa1 = *(const s16x8*)(qp + 32);

  const f32x4 fzero = {0.f, 0.f, 0.f, 0.f};
  f32x4 acc[4];
#pragma unroll
  for (int d = 0; d < 4; ++d) acc[d] = fzero;
  float rs[4] = {0.f, 0.f, 0.f, 0.f};

  const int rkA = tid >> 3, cA = tid & 7, csA = cA ^ (rkA & 7);
  const int ci2 = tid + 256;
  const int rkB = ci2 >> 3, cB = ci2 & 7, csB = cB ^ (rkB & 7);

  for (int kt = 0; kt < 32; ++kt) {
    const int kb = kt * 64;
    async16(KbS + tid * 8, Kbf + ((bh * 2048 + kb + rkA) * 64) + csA * 8);
    async16(VtS + tid * 8, Vt + ((bh * 64 + rkA) * 2048) + kb + csA * 8);
    async16(KbS + ci2 * 8, Kbf + ((bh * 2048 + kb + rkB) * 64) + csB * 8);
    async16(VtS + ci2 * 8, Vt + ((bh * 64 + rkB) * 2048) + kb + csB * 8);
    __syncthreads();

    f32x4 sc[4];
#pragma unroll
    for (int fn = 0; fn < 4; ++fn) {
      int key = fn * 16 + l15;
      s16x8 kf0 = *(const s16x8*)(KbS + key * 64 + ((l4 ^ (key & 7)) * 8));
      s16x8 kf1 = *(const s16x8*)(KbS + key * 64 + (((l4 + 4) ^ (key & 7)) * 8));
      sc[fn] = __builtin_amdgcn_mfma_f32_16x16x32_bf16(qa0, kf0, fzero, 0, 0, 0);
      sc[fn] = __builtin_amdgcn_mfma_f32_16x16x32_bf16(qa1, kf1, sc[fn], 0, 0, 0);
    }

#pragma unroll
    for (int fn = 0; fn < 4; ++fn) {
      int wi = kt * 2 + (fn >> 1);
      u32x4 mw = *(const u32x4*)(maskT + wi * 68 + w * 16 + l4 * 4);
      u32 bp = (u32)((fn & 1) * 16 + l15);
#pragma unroll
      for (int r = 0; r < 4; ++r) {
        float sv = ((mw[r] >> bp) & 1u) ? sc[fn][r] : 0.0f;
        float p = __expf(sv);          // masked -> exp(0)=1, stays in softmax
        rs[r] += p;
        Pls[w][(l4 * 4 + r) * 72 + fn * 16 + l15] = f2bf(p);
      }
    }

    s16x8 pa0 = *(const s16x8*)(Pls[w] + l15 * 72 + l4 * 8);
    s16x8 pa1 = *(const s16x8*)(Pls[w] + l15 * 72 + l4 * 8 + 32);
#pragma unroll
    for (int df = 0; df < 4; ++df) {
      int dl = df * 16 + l15;
      s16x8 vf0 = *(const s16x8*)(VtS + dl * 64 + ((l4 ^ (dl & 7)) * 8));
      s16x8 vf1 = *(const s16x8*)(VtS + dl * 64 + (((l4 + 4) ^ (dl & 7)) * 8));
      acc[df] = __builtin_amdgcn_mfma_f32_16x16x32_bf16(pa0, vf0, acc[df], 0, 0, 0);
      acc[df] = __builtin_amdgcn_mfma_f32_16x16x32_bf16(pa1, vf1, acc[df], 0, 0, 0);
    }
    __syncthreads();
  }

#pragma unroll
  for (int r = 0; r < 4; ++r) {   // sum over the 16 key-columns held per lane-group
    float v = rs[r];
    v += __shfl_xor(v, 1); v += __shfl_xor(v, 2);
    v += __shfl_xor(v, 4); v += __shfl_xor(v, 8);
    rs[r] = 1.0f / v;
  }
  const int b = bh >> 4, h = bh & 15;
#pragma unroll
  for (int df = 0; df < 4; ++df) {
    int col = h * 64 + df * 16 + l15;
#pragma unroll
    for (int r = 0; r < 4; ++r) {
      int qg = qbase + w * 16 + l4 * 4 + r;
      out[(b * 2048 + qg) * 1024 + col] = acc[df][r] * rs[r];
    }
  }
}

// ---------------------------------------------------------------------------
extern "C" void kernel_launch(void* const* d_in, const int* in_sizes, int n_in,
                              void* d_out, int out_size, void* d_ws, size_t ws_size,
                              hipStream_t stream) {
  const float* hs = (const float*)d_in[0];
  const float* Wq = (const float*)d_in[1];
  const float* bq = (const float*)d_in[2];
  const float* Wk = (const float*)d_in[3];
  const float* bk = (const float*)d_in[4];
  const float* Wv = (const float*)d_in[5];
  const float* bv = (const float*)d_in[6];
  float* out = (float*)d_out;
  char* ws = (char*)d_ws;

  u32* maskbits = (u32*)(ws);                       // 512 KB
  u16* Xbf  = (u16*)(ws + 524288);                  // 8 MB  [4096][1024]
  u16* Wbf3 = (u16*)(ws + 524288 + 8388608);        // 6 MB  3x[1024][1024]
  u16* Qbf  = (u16*)(ws + 15204352);                // 8 MB  [bh][s][d]
  u16* Kbf  = (u16*)(ws + 23592960);                // 8 MB  [bh][s][d]
  u16* Vt   = (u16*)(ws + 31981568);                // 8 MB  [bh][d][s]

  cast_kernel<<<4096, 256, 0, stream>>>(hs, Xbf, 1048576);
  cast_kernel<<<1024, 256, 0, stream>>>(Wq, Wbf3,           262144);
  cast_kernel<<<1024, 256, 0, stream>>>(Wk, Wbf3 + 1048576, 262144);
  cast_kernel<<<1024, 256, 0, stream>>>(Wv, Wbf3 + 2097152, 262144);
  mask_kernel<<<2048, 256, 0, stream>>>(maskbits);
  gemm_qkv<<<dim3(32, 8, 3), 256, 0, stream>>>(Xbf, Wbf3, bq, bk, bv, Qbf, Kbf, Vt);
  attn_kernel<<<dim3(32, 32), 256, 0, stream>>>(Qbf, Kbf, Vt, maskbits, out);
}